// Round 12
// baseline (440.764 us; speedup 1.0000x reference)
//
#include <hip/hip_runtime.h>
#include <hip/hip_bf16.h>
#include <math.h>

// ---------- constants ----------
// B=32, H=W=56, C=192, WS=7, SS=3, NH=6, HD=32, N=49, NW=64
#define MTOK 100352
#define SCALE_ 0.17677669529663687f

typedef short bf16x8 __attribute__((ext_vector_type(8)));
typedef float f32x4 __attribute__((ext_vector_type(4)));

__device__ __forceinline__ float b2f(unsigned short u) {
    return __uint_as_float(((unsigned int)u) << 16);
}
__device__ __forceinline__ unsigned short f2b(float f) {
    unsigned int u = __float_as_uint(f);
    unsigned int r = (u + 0x7FFFu + ((u >> 16) & 1u)) >> 16;
    return (unsigned short)r;
}
__device__ __forceinline__ void gload_lds16(const unsigned short* g, unsigned short* l) {
    __builtin_amdgcn_global_load_lds(
        (const __attribute__((address_space(1))) void*)g,
        (__attribute__((address_space(3))) void*)l, 16, 0, 0);
}

// ---------- weight convert+transpose: W[K][N] f32 -> W^T[N][K] bf16 ----------
__global__ __launch_bounds__(256) void wconv_k(
    const float* __restrict__ w, unsigned short* __restrict__ wt, int K, int N)
{
    const int i = blockIdx.x * 256 + threadIdx.x;
    if (i >= N * K) return;
    const int n = i / K, k = i - n * K;
    wt[i] = f2b(w[(size_t)k * N + n]);
}

// ---------- LN1 + cyclic shift + window partition ----------
__global__ __launch_bounds__(256) void ln1_window_k(
    const float* __restrict__ x, const float* __restrict__ g,
    const float* __restrict__ bt, unsigned short* __restrict__ out)
{
    const int wid = (blockIdx.x * 256 + threadIdx.x) >> 6;
    if (wid >= MTOK) return;
    const int lane = threadIdx.x & 63;
    const int widx = wid / 49, n = wid - widx * 49;
    const int b = widx >> 6, win = widx & 63;
    const int wh = win >> 3, ww = win & 7;
    const int r = n / 7, cc = n - r * 7;
    int hh = wh * 7 + r + 3;  if (hh >= 56) hh -= 56;
    int wc = ww * 7 + cc + 3; if (wc >= 56) wc -= 56;
    const size_t src = ((size_t)b * 3136 + hh * 56 + wc) * 192;
    const float v0 = x[src + lane], v1 = x[src + lane + 64], v2 = x[src + lane + 128];
    float s1 = v0 + v1 + v2;
    float s2 = v0 * v0 + v1 * v1 + v2 * v2;
    #pragma unroll
    for (int off = 32; off; off >>= 1) {
        s1 += __shfl_xor(s1, off, 64);
        s2 += __shfl_xor(s2, off, 64);
    }
    const float mu = s1 * (1.f / 192.f);
    const float var = s2 * (1.f / 192.f) - mu * mu;
    const float rs = rsqrtf(var + 1e-5f);
    const size_t dst = (size_t)wid * 192;
    out[dst + lane]       = f2b((v0 - mu) * rs * g[lane]       + bt[lane]);
    out[dst + lane + 64]  = f2b((v1 - mu) * rs * g[lane + 64]  + bt[lane + 64]);
    out[dst + lane + 128] = f2b((v2 - mu) * rs * g[lane + 128] + bt[lane + 128]);
}

// ---------- LN2 (token-order) ----------
__global__ __launch_bounds__(256) void ln2_k(
    const float* __restrict__ x, const float* __restrict__ g,
    const float* __restrict__ bt, unsigned short* __restrict__ out)
{
    const int t = (blockIdx.x * 256 + threadIdx.x) >> 6;
    if (t >= MTOK) return;
    const int lane = threadIdx.x & 63;
    const size_t src = (size_t)t * 192;
    const float v0 = x[src + lane], v1 = x[src + lane + 64], v2 = x[src + lane + 128];
    float s1 = v0 + v1 + v2;
    float s2 = v0 * v0 + v1 * v1 + v2 * v2;
    #pragma unroll
    for (int off = 32; off; off >>= 1) {
        s1 += __shfl_xor(s1, off, 64);
        s2 += __shfl_xor(s2, off, 64);
    }
    const float mu = s1 * (1.f / 192.f);
    const float var = s2 * (1.f / 192.f) - mu * mu;
    const float rs = rsqrtf(var + 1e-5f);
    out[src + lane]       = f2b((v0 - mu) * rs * g[lane]       + bt[lane]);
    out[src + lane + 64]  = f2b((v1 - mu) * rs * g[lane + 64]  + bt[lane + 64]);
    out[src + lane + 128] = f2b((v2 - mu) * rs * g[lane + 128] + bt[lane + 128]);
}

// ---------- MFMA GEMM, barrier-free K-loop ----------
// C[M,N] = A[M,K](bf16) @ W^T[N][K](bf16). Block: 256 rows x 64 cols, 4 waves,
// each wave 64x64 (4x4 frags). B strip (64 x K) resident in LDS, staged ONCE per
// Kc<=256 chunk (fc1/qkv/proj: single chunk -> ONE barrier total; fc2: 3 chunks).
// A is streamed per-wave from global into registers (each 16B read by exactly one
// lane; A fetched once). B LDS uses the verified chunk swizzle:
//   store col ((lane&3)^((lane>>3)&3))*8, read col (l4^((l16>>1)&3))*8 -> 0 conflicts.
enum { EPI_STORE_BF16 = 0, EPI_PROJ = 1, EPI_GELU = 2, EPI_RES = 3 };

template <int EPI, int K>
__global__ __launch_bounds__(256) void mgemm_k(
    const unsigned short* __restrict__ A, const unsigned short* __restrict__ BT,
    const float* __restrict__ bias, unsigned short* __restrict__ outb,
    float* __restrict__ outf, const float* __restrict__ xres,
    int N, int gx)
{
    constexpr int KC = (K < 256) ? K : 256;   // chunk size (elements)
    constexpr int NCH = KC / 32;              // 32-col sub-chunks per chunk
    constexpr int NKC = K / KC;               // chunks
    __shared__ __align__(16) unsigned short Bs[64 * KC];

    // bijective XCD swizzle (nwg % 8 == 0 for all our launches)
    const int nwg = gridDim.x;
    int lin = blockIdx.x;
    lin = (lin & 7) * (nwg >> 3) + (lin >> 3);
    const int bn = lin % gx, bm = lin / gx;
    const int row0 = bm * 256, col0 = bn * 64;

    const int tid = threadIdx.x;
    const int w = tid >> 6, lane = tid & 63;
    const int l16 = lane & 15, l4 = lane >> 4;

    const unsigned short* Bb = BT + (size_t)col0 * K;
    const int sr = lane >> 2;                              // row within 16-row group
    const int sq = ((lane & 3) ^ ((lane >> 3) & 3)) * 8;   // inverse-swizzled source col
    const int rdc = (l4 ^ ((l16 >> 1) & 3)) * 8;           // swizzled read col

    // wave-private A base: rows row0 + w*64 + m*16 + l16, col chunk l4*8
    const unsigned short* Aw = A + (size_t)(row0 + w * 64 + l16) * K + l4 * 8;

    f32x4 acc[4][4];
    #pragma unroll
    for (int m = 0; m < 4; m++)
        #pragma unroll
        for (int n = 0; n < 4; n++) acc[m][n] = (f32x4){0.f, 0.f, 0.f, 0.f};

    for (int kc = 0; kc < NKC; ++kc) {
        const int kbase = kc * KC;
        // stage B chunk (NCH*4 gload_lds16, distributed over the 4 waves)
        #pragma unroll
        for (int p = w; p < NCH * 4; p += 4) {
            const int ck = p >> 2, rg = p & 3;
            gload_lds16(Bb + (size_t)(rg * 16 + sr) * K + kbase + ck * 32 + sq,
                        &Bs[ck * 2048 + rg * 512 + lane * 8]);
        }
        __syncthreads();
        // barrier-free K loop over this chunk
        #pragma unroll
        for (int ks = 0; ks < NCH; ++ks) {
            const int k = kbase + ks * 32;
            bf16x8 af[4], bf[4];
            #pragma unroll
            for (int m = 0; m < 4; m++)
                af[m] = *reinterpret_cast<const bf16x8*>(Aw + (size_t)(m * 16) * K + k);
            #pragma unroll
            for (int n = 0; n < 4; n++)
                bf[n] = *reinterpret_cast<const bf16x8*>(
                    &Bs[ks * 2048 + (n * 16 + l16) * 32 + rdc]);
            #pragma unroll
            for (int m = 0; m < 4; m++)
                #pragma unroll
                for (int n = 0; n < 4; n++)
                    acc[m][n] = __builtin_amdgcn_mfma_f32_16x16x32_bf16(
                        af[m], bf[n], acc[m][n], 0, 0, 0);
        }
        if (kc + 1 < NKC) __syncthreads();   // before restaging Bs
    }

    // epilogue: frag (m,n) reg j -> row = row0+w*64+m*16+l4*4+j, col = col0+n*16+l16
    float bv[4];
    #pragma unroll
    for (int n = 0; n < 4; n++) bv[n] = bias[col0 + n * 16 + l16];

    #pragma unroll
    for (int m = 0; m < 4; m++) {
        #pragma unroll
        for (int j = 0; j < 4; j++) {
            const int row = row0 + w * 64 + m * 16 + l4 * 4 + j;
            if constexpr (EPI == EPI_PROJ) {
                const int widx = row / 49, n49 = row - widx * 49;
                const int b = widx >> 6, win = widx & 63;
                const int wh = win >> 3, ww = win & 7;
                const int r = n49 / 7, cc = n49 - r * 7;
                int hh = wh * 7 + r + 3;  if (hh >= 56) hh -= 56;
                int wcc = ww * 7 + cc + 3; if (wcc >= 56) wcc -= 56;
                const size_t tok = ((size_t)b * 3136 + hh * 56 + wcc) * 192;
                #pragma unroll
                for (int n = 0; n < 4; n++) {
                    const int col = col0 + n * 16 + l16;
                    outf[tok + col] = xres[tok + col] + acc[m][n][j] + bv[n];
                }
            } else if constexpr (EPI == EPI_STORE_BF16) {
                #pragma unroll
                for (int n = 0; n < 4; n++) {
                    const int col = col0 + n * 16 + l16;
                    outb[(size_t)row * N + col] = f2b(acc[m][n][j] + bv[n]);
                }
            } else if constexpr (EPI == EPI_GELU) {
                #pragma unroll
                for (int n = 0; n < 4; n++) {
                    const int col = col0 + n * 16 + l16;
                    float v = acc[m][n][j] + bv[n];
                    // tanh-form GELU (|err| <= 3e-3 vs exact erf form)
                    const float y = 0.7978845608028654f * (v + 0.044715f * v * v * v);
                    const float e2 = __expf(2.f * y);
                    const float th = 1.f - 2.f / (e2 + 1.f);
                    v = 0.5f * v * (1.f + th);
                    outb[(size_t)row * N + col] = f2b(v);
                }
            } else {  // EPI_RES
                #pragma unroll
                for (int n = 0; n < 4; n++) {
                    const int col = col0 + n * 16 + l16;
                    outf[(size_t)row * N + col] += acc[m][n][j] + bv[n];
                }
            }
        }
    }
}

// ---------- MFMA attention: one wave (64 thr) per (window, head) ----------
__global__ __launch_bounds__(64) void attn_mfma_k(
    const unsigned short* __restrict__ qkv, const float* __restrict__ rpb,
    unsigned short* __restrict__ out)
{
    const int blk = blockIdx.x;
    const int widx = blk / 6, head = blk - widx * 6;
    const int win = widx & 63;
    const int wh = win >> 3, ww = win & 7;

    __shared__ __align__(16) unsigned short vt[32 * 72];  // V^T [d][m], stride 72
    __shared__ __align__(16) unsigned short pl[64 * 72];  // P  [n][m], stride 72
    __shared__ float bias_s[256];                          // 169 used (+ OOB slack)

    const int lane = threadIdx.x;
    const int l16 = lane & 15, l4 = lane >> 4;
    const size_t base = (size_t)widx * 49 * 576 + (size_t)head * 32;

    for (int i = lane; i < 169; i += 64) bias_s[i] = rpb[i * 6 + head];

    // stage V^T with zero-fill for m in [49,64)
    #pragma unroll
    for (int it = 0; it < 4; ++it) {
        const int c = lane + it * 64;            // 0..255
        const int m = c >> 2, d8 = (c & 3) * 8;
        bf16x8 v8 = {};
        if (m < 49)
            v8 = *reinterpret_cast<const bf16x8*>(qkv + base + (size_t)m * 576 + 384 + d8);
        #pragma unroll
        for (int r = 0; r < 8; ++r) vt[(d8 + r) * 72 + m] = (unsigned short)v8[r];
    }

    // K (A-op) and Q (B-op) fragments: row = f*16+l16, d = l4*8..+7
    bf16x8 kf[4], qf[4];
    #pragma unroll
    for (int f = 0; f < 4; ++f) {
        const int rrow = f * 16 + l16;
        bf16x8 kz = {}, qz = {};
        if (rrow < 49) {
            kz = *reinterpret_cast<const bf16x8*>(qkv + base + (size_t)rrow * 576 + 192 + l4 * 8);
            qz = *reinterpret_cast<const bf16x8*>(qkv + base + (size_t)rrow * 576 + l4 * 8);
        }
        kf[f] = kz; qf[f] = qz;
    }

    // QK^T: acc[mf][nf][j] = S[m = mf*16+l4*4+j][n = nf*16+l16]
    f32x4 acc[4][4];
    #pragma unroll
    for (int mf = 0; mf < 4; ++mf)
        #pragma unroll
        for (int nf = 0; nf < 4; ++nf) {
            f32x4 z = (f32x4){0.f, 0.f, 0.f, 0.f};
            acc[mf][nf] = __builtin_amdgcn_mfma_f32_16x16x32_bf16(kf[mf], qf[nf], z, 0, 0, 0);
        }

    __syncthreads();   // vt + bias_s visible

    // geometry: g(t) = t + 6*(t/7); bias idx = g(n) - g(m) + 84
    int gn[4], labn[4]; bool nok[4];
    #pragma unroll
    for (int nf = 0; nf < 4; ++nf) {
        const int n = nf * 16 + l16;
        const int rn = (n * 9363) >> 16, cn = n - rn * 7;
        gn[nf] = n + 6 * rn;
        labn[nf] = (wh == 7 ? (rn < 4 ? 1 : 2) : 0) * 3 + (ww == 7 ? (cn < 4 ? 1 : 2) : 0);
        nok[nf] = (n < 49);
    }

    // scale + bias + mask (in-register)
    #pragma unroll
    for (int mf = 0; mf < 4; ++mf) {
        #pragma unroll
        for (int j = 0; j < 4; ++j) {
            const int m = mf * 16 + l4 * 4 + j;
            const int rm = (m * 9363) >> 16, cm = m - rm * 7;
            const int gm = m + 6 * rm;
            const int labm = (wh == 7 ? (rm < 4 ? 1 : 2) : 0) * 3 + (ww == 7 ? (cm < 4 ? 1 : 2) : 0);
            const bool mok = (m < 49);
            #pragma unroll
            for (int nf = 0; nf < 4; ++nf) {
                float s = -1e30f;
                if (mok && nok[nf]) {
                    s = acc[mf][nf][j] * SCALE_ + bias_s[gn[nf] - gm + 84];
                    if (labn[nf] != labm) s -= 100.f;
                }
                acc[mf][nf][j] = s;
            }
        }
    }

    // softmax over m per n-column; write normalized bf16 P to LDS
    #pragma unroll
    for (int nf = 0; nf < 4; ++nf) {
        float mx = -1e30f;
        #pragma unroll
        for (int mf = 0; mf < 4; ++mf)
            #pragma unroll
            for (int j = 0; j < 4; ++j) mx = fmaxf(mx, acc[mf][nf][j]);
        mx = fmaxf(mx, __shfl_xor(mx, 16, 64));
        mx = fmaxf(mx, __shfl_xor(mx, 32, 64));
        float sum = 0.f;
        #pragma unroll
        for (int mf = 0; mf < 4; ++mf)
            #pragma unroll
            for (int j = 0; j < 4; ++j) {
                const float e = __expf(acc[mf][nf][j] - mx);
                acc[mf][nf][j] = e;
                sum += e;
            }
        sum += __shfl_xor(sum, 16, 64);
        sum += __shfl_xor(sum, 32, 64);
        const float inv = 1.f / sum;
        const int n = nf * 16 + l16;
        #pragma unroll
        for (int mf = 0; mf < 4; ++mf)
            #pragma unroll
            for (int jp = 0; jp < 2; ++jp) {
                const int m = mf * 16 + l4 * 4 + jp * 2;
                const unsigned int pk =
                    (unsigned int)f2b(acc[mf][nf][jp * 2] * inv) |
                    ((unsigned int)f2b(acc[mf][nf][jp * 2 + 1] * inv) << 16);
                *reinterpret_cast<unsigned int*>(&pl[n * 72 + m]) = pk;
            }
    }
    __syncthreads();

    // PV: out[n][d] = P @ V ; A=P rows n, B=V^T rows d, K=m (2 ksteps)
    f32x4 oacc[4][2];
    #pragma unroll
    for (int nf = 0; nf < 4; ++nf)
        #pragma unroll
        for (int df = 0; df < 2; ++df) oacc[nf][df] = (f32x4){0.f, 0.f, 0.f, 0.f};
    #pragma unroll
    for (int ks = 0; ks < 2; ++ks) {
        bf16x8 vf[2];
        #pragma unroll
        for (int df = 0; df < 2; ++df)
            vf[df] = *reinterpret_cast<const bf16x8*>(&vt[(df * 16 + l16) * 72 + ks * 32 + l4 * 8]);
        #pragma unroll
        for (int nf = 0; nf < 4; ++nf) {
            const bf16x8 pf = *reinterpret_cast<const bf16x8*>(&pl[(nf * 16 + l16) * 72 + ks * 32 + l4 * 8]);
            #pragma unroll
            for (int df = 0; df < 2; ++df)
                oacc[nf][df] = __builtin_amdgcn_mfma_f32_16x16x32_bf16(pf, vf[df], oacc[nf][df], 0, 0, 0);
        }
    }

    // write out: row n = nf*16+l4*4+j, col d = df*16+l16
    #pragma unroll
    for (int nf = 0; nf < 4; ++nf)
        #pragma unroll
        for (int j = 0; j < 4; ++j) {
            const int n = nf * 16 + l4 * 4 + j;
            if (n < 49) {
                const size_t o = ((size_t)widx * 49 + n) * 192 + (size_t)head * 32;
                out[o + l16]      = f2b(oacc[nf][0][j]);
                out[o + 16 + l16] = f2b(oacc[nf][1][j]);
            }
        }
}

// ---------- launch ----------
extern "C" void kernel_launch(void* const* d_in, const int* in_sizes, int n_in,
                              void* d_out, int out_size, void* d_ws, size_t ws_size,
                              hipStream_t stream)
{
    const float* x      = (const float*)d_in[0];
    const float* n1g    = (const float*)d_in[1];
    const float* n1b    = (const float*)d_in[2];
    const float* qkv_w  = (const float*)d_in[3];
    const float* qkv_b  = (const float*)d_in[4];
    const float* rpb    = (const float*)d_in[5];
    const float* proj_w = (const float*)d_in[6];
    const float* proj_b = (const float*)d_in[7];
    const float* n2g    = (const float*)d_in[8];
    const float* n2b    = (const float*)d_in[9];
    const float* fc1_w  = (const float*)d_in[10];
    const float* fc1_b  = (const float*)d_in[11];
    const float* fc2_w  = (const float*)d_in[12];
    const float* fc2_b  = (const float*)d_in[13];
    float* out = (float*)d_out;

    const int M = MTOK;  // 100352 = 392*256
    unsigned short* big   = (unsigned short*)d_ws;          // M*768
    unsigned short* winx  = big + (size_t)M * 768;          // M*192 (ln1-win, attn-out, ln2-out)
    unsigned short* qkvT  = winx + (size_t)M * 192;         // 576*192
    unsigned short* projT = qkvT + 576 * 192;               // 192*192
    unsigned short* fc1T  = projT + 192 * 192;              // 768*192
    unsigned short* fc2T  = fc1T + 768 * 192;               // 192*768

    // 0) weights -> bf16 transposed
    wconv_k<<<(576 * 192 + 255) / 256, 256, 0, stream>>>(qkv_w, qkvT, 192, 576);
    wconv_k<<<(192 * 192 + 255) / 256, 256, 0, stream>>>(proj_w, projT, 192, 192);
    wconv_k<<<(768 * 192 + 255) / 256, 256, 0, stream>>>(fc1_w, fc1T, 192, 768);
    wconv_k<<<(192 * 768 + 255) / 256, 256, 0, stream>>>(fc2_w, fc2T, 768, 192);

    // 1) LN1 + shift + window partition -> winx (bf16)
    ln1_window_k<<<M / 4, 256, 0, stream>>>(x, n1g, n1b, winx);
    // 2) qkv: (M,192)@(192,576) -> big
    mgemm_k<EPI_STORE_BF16, 192><<<9 * (M / 256), 256, 0, stream>>>(
        winx, qkvT, qkv_b, big, nullptr, nullptr, 576, 9);
    // 3) attention (MFMA, one wave per window×head) -> winx
    attn_mfma_k<<<2048 * 6, 64, 0, stream>>>(big, rpb, winx);
    // 4) proj + window-reverse + unshift + residual -> d_out (f32)
    mgemm_k<EPI_PROJ, 192><<<3 * (M / 256), 256, 0, stream>>>(
        winx, projT, proj_b, nullptr, out, x, 192, 3);
    // 5) LN2 -> winx (bf16)
    ln2_k<<<M / 4, 256, 0, stream>>>(out, n2g, n2b, winx);
    // 6) fc1 + GELU -> big
    mgemm_k<EPI_GELU, 192><<<12 * (M / 256), 256, 0, stream>>>(
        winx, fc1T, fc1_b, big, nullptr, nullptr, 768, 12);
    // 7) fc2 + residual -> d_out
    mgemm_k<EPI_RES, 768><<<3 * (M / 256), 256, 0, stream>>>(
        big, fc2T, fc2_b, nullptr, out, nullptr, 192, 3);
}

// Round 13
// 405.480 us; speedup vs baseline: 1.0870x; 1.0870x over previous
//
#include <hip/hip_runtime.h>
#include <hip/hip_bf16.h>
#include <math.h>

// ---------- constants ----------
// B=32, H=W=56, C=192, WS=7, SS=3, NH=6, HD=32, N=49, NW=64
#define MTOK 100352
#define SCALE_ 0.17677669529663687f

typedef short bf16x8 __attribute__((ext_vector_type(8)));
typedef float f32x4 __attribute__((ext_vector_type(4)));

__device__ __forceinline__ float b2f(unsigned short u) {
    return __uint_as_float(((unsigned int)u) << 16);
}
__device__ __forceinline__ unsigned short f2b(float f) {
    unsigned int u = __float_as_uint(f);
    unsigned int r = (u + 0x7FFFu + ((u >> 16) & 1u)) >> 16;
    return (unsigned short)r;
}
__device__ __forceinline__ void gload_lds16(const unsigned short* g, unsigned short* l) {
    __builtin_amdgcn_global_load_lds(
        (const __attribute__((address_space(1))) void*)g,
        (__attribute__((address_space(3))) void*)l, 16, 0, 0);
}

// ---------- weight convert+transpose: W[K][N] f32 -> W^T[N][K] bf16 ----------
__global__ __launch_bounds__(256) void wconv_k(
    const float* __restrict__ w, unsigned short* __restrict__ wt, int K, int N)
{
    const int i = blockIdx.x * 256 + threadIdx.x;
    if (i >= N * K) return;
    const int n = i / K, k = i - n * K;
    wt[i] = f2b(w[(size_t)k * N + n]);
}

// ---------- LN1 + cyclic shift + window partition ----------
__global__ __launch_bounds__(256) void ln1_window_k(
    const float* __restrict__ x, const float* __restrict__ g,
    const float* __restrict__ bt, unsigned short* __restrict__ out)
{
    const int wid = (blockIdx.x * 256 + threadIdx.x) >> 6;
    if (wid >= MTOK) return;
    const int lane = threadIdx.x & 63;
    const int widx = wid / 49, n = wid - widx * 49;
    const int b = widx >> 6, win = widx & 63;
    const int wh = win >> 3, ww = win & 7;
    const int r = n / 7, cc = n - r * 7;
    int hh = wh * 7 + r + 3;  if (hh >= 56) hh -= 56;
    int wc = ww * 7 + cc + 3; if (wc >= 56) wc -= 56;
    const size_t src = ((size_t)b * 3136 + hh * 56 + wc) * 192;
    const float v0 = x[src + lane], v1 = x[src + lane + 64], v2 = x[src + lane + 128];
    float s1 = v0 + v1 + v2;
    float s2 = v0 * v0 + v1 * v1 + v2 * v2;
    #pragma unroll
    for (int off = 32; off; off >>= 1) {
        s1 += __shfl_xor(s1, off, 64);
        s2 += __shfl_xor(s2, off, 64);
    }
    const float mu = s1 * (1.f / 192.f);
    const float var = s2 * (1.f / 192.f) - mu * mu;
    const float rs = rsqrtf(var + 1e-5f);
    const size_t dst = (size_t)wid * 192;
    out[dst + lane]       = f2b((v0 - mu) * rs * g[lane]       + bt[lane]);
    out[dst + lane + 64]  = f2b((v1 - mu) * rs * g[lane + 64]  + bt[lane + 64]);
    out[dst + lane + 128] = f2b((v2 - mu) * rs * g[lane + 128] + bt[lane + 128]);
}

// ---------- MFMA GEMM (R10 structure): C[M,N] = A[M,K](bf16) @ W^T[N][K](bf16) ----------
// tile 128x64, BK=32, DOUBLE-buffered global_load_lds (24 KB).
// 4 waves in 2x2, each wave 64x32 (4x2 frags of 16x16x32), 8 MFMA / K-step.
// Swizzle (both-sides-or-neither): source col ((lane&3)^((lane>>3)&3))*8,
// read col (l4^((l16>>1)&3))*8 -> 0 conflicts (verified R10 counter).
enum { EPI_STORE_BF16 = 0, EPI_GELU = 2, EPI_RES = 3 };

template <int EPI>
__global__ __launch_bounds__(256) void mgemm_k(
    const unsigned short* __restrict__ A, const unsigned short* __restrict__ BT,
    const float* __restrict__ bias, unsigned short* __restrict__ outb,
    float* __restrict__ outf, int N, int K, int gx)
{
    __shared__ __align__(16) unsigned short As[2][128 * 32];  // 2x8 KB
    __shared__ __align__(16) unsigned short Bs[2][64 * 32];   // 2x4 KB

    const int nwg = gridDim.x;
    int lin = blockIdx.x;
    lin = (lin & 7) * (nwg >> 3) + (lin >> 3);
    const int bn = lin % gx, bm = lin / gx;
    const int row0 = bm * 128, col0 = bn * 64;

    const int tid = threadIdx.x;
    const int w = tid >> 6, lane = tid & 63;
    const int wr = w >> 1, wc = w & 1;
    const int l16 = lane & 15, l4 = lane >> 4;

    const unsigned short* Ab = A + (size_t)row0 * K;
    const unsigned short* Bb = BT + (size_t)col0 * K;
    const int sr = lane >> 2;
    const int sq = ((lane & 3) ^ ((lane >> 3) & 3)) * 8;

    #pragma unroll
    for (int i = 0; i < 2; i++) {
        const int ch = w * 2 + i;
        gload_lds16(Ab + (size_t)(ch * 16 + sr) * K + sq, &As[0][ch * 512 + lane * 8]);
    }
    gload_lds16(Bb + (size_t)(w * 16 + sr) * K + sq, &Bs[0][w * 512 + lane * 8]);
    __syncthreads();

    f32x4 acc[4][2];
    #pragma unroll
    for (int m = 0; m < 4; m++)
        #pragma unroll
        for (int n = 0; n < 2; n++) acc[m][n] = (f32x4){0.f, 0.f, 0.f, 0.f};

    const int rdc = (l4 ^ ((l16 >> 1) & 3)) * 8;
    const int nt = K >> 5;
    for (int t = 0; t < nt; ++t) {
        const int cur = t & 1;
        if (t + 1 < nt) {
            const int k0 = (t + 1) << 5;
            #pragma unroll
            for (int i = 0; i < 2; i++) {
                const int ch = w * 2 + i;
                gload_lds16(Ab + (size_t)(ch * 16 + sr) * K + k0 + sq,
                            &As[cur ^ 1][ch * 512 + lane * 8]);
            }
            gload_lds16(Bb + (size_t)(w * 16 + sr) * K + k0 + sq,
                        &Bs[cur ^ 1][w * 512 + lane * 8]);
        }
        bf16x8 af[4], bf[2];
        #pragma unroll
        for (int m = 0; m < 4; m++)
            af[m] = *reinterpret_cast<const bf16x8*>(
                &As[cur][(wr * 64 + m * 16 + l16) * 32 + rdc]);
        #pragma unroll
        for (int n = 0; n < 2; n++)
            bf[n] = *reinterpret_cast<const bf16x8*>(
                &Bs[cur][(wc * 32 + n * 16 + l16) * 32 + rdc]);
        #pragma unroll
        for (int m = 0; m < 4; m++)
            #pragma unroll
            for (int n = 0; n < 2; n++)
                acc[m][n] = __builtin_amdgcn_mfma_f32_16x16x32_bf16(
                    af[m], bf[n], acc[m][n], 0, 0, 0);
        __syncthreads();
    }

    float bv[2];
    #pragma unroll
    for (int n = 0; n < 2; n++) bv[n] = bias[col0 + wc * 32 + n * 16 + l16];

    #pragma unroll
    for (int m = 0; m < 4; m++) {
        #pragma unroll
        for (int j = 0; j < 4; j++) {
            const int row = row0 + wr * 64 + m * 16 + l4 * 4 + j;
            if constexpr (EPI == EPI_STORE_BF16) {
                #pragma unroll
                for (int n = 0; n < 2; n++) {
                    const int col = col0 + wc * 32 + n * 16 + l16;
                    outb[(size_t)row * N + col] = f2b(acc[m][n][j] + bv[n]);
                }
            } else if constexpr (EPI == EPI_GELU) {
                #pragma unroll
                for (int n = 0; n < 2; n++) {
                    const int col = col0 + wc * 32 + n * 16 + l16;
                    float v = acc[m][n][j] + bv[n];
                    const float y = 0.7978845608028654f * (v + 0.044715f * v * v * v);
                    const float e2 = __expf(2.f * y);
                    v = 0.5f * v * (2.f - 2.f / (e2 + 1.f));
                    outb[(size_t)row * N + col] = f2b(v);
                }
            } else {  // EPI_RES
                #pragma unroll
                for (int n = 0; n < 2; n++) {
                    const int col = col0 + wc * 32 + n * 16 + l16;
                    outf[(size_t)row * N + col] += acc[m][n][j] + bv[n];
                }
            }
        }
    }
}

// ---------- proj GEMM + window-reverse + residual + LN2 fused ----------
// tile 128 rows x FULL 192 cols, 4 waves; wave w: rows [w*32,w*32+32) (2 m-frags),
// all 12 n-frags. Epilogue: v = x + proj + bias (12/lane), 16-lane shfl reduce for
// mean/var, write x2 (f32 -> d_out) and xn = LN2(x2) (bf16, token order).
__global__ __launch_bounds__(256) void projln_k(
    const unsigned short* __restrict__ A, const unsigned short* __restrict__ BT,
    const float* __restrict__ bias, const float* __restrict__ xres,
    const float* __restrict__ g2, const float* __restrict__ b2,
    float* __restrict__ x2, unsigned short* __restrict__ xn)
{
    constexpr int K = 192;
    __shared__ __align__(16) unsigned short As[2][128 * 32];  // 2x8 KB
    __shared__ __align__(16) unsigned short Bs[2][192 * 32];  // 2x12 KB

    const int nwg = gridDim.x;
    int lin = blockIdx.x;
    lin = (lin & 7) * (nwg >> 3) + (lin >> 3);
    const int row0 = lin * 128;

    const int tid = threadIdx.x;
    const int w = tid >> 6, lane = tid & 63;
    const int l16 = lane & 15, l4 = lane >> 4;

    const unsigned short* Ab = A + (size_t)row0 * K;
    const int sr = lane >> 2;
    const int sq = ((lane & 3) ^ ((lane >> 3) & 3)) * 8;

    #pragma unroll
    for (int i = 0; i < 2; i++) {
        const int ch = w * 2 + i;
        gload_lds16(Ab + (size_t)(ch * 16 + sr) * K + sq, &As[0][ch * 512 + lane * 8]);
    }
    #pragma unroll
    for (int i = 0; i < 3; i++) {
        const int ch = w * 3 + i;
        gload_lds16(BT + (size_t)(ch * 16 + sr) * K + sq, &Bs[0][ch * 512 + lane * 8]);
    }
    __syncthreads();

    f32x4 acc[2][12];
    #pragma unroll
    for (int m = 0; m < 2; m++)
        #pragma unroll
        for (int n = 0; n < 12; n++) acc[m][n] = (f32x4){0.f, 0.f, 0.f, 0.f};

    const int rdc = (l4 ^ ((l16 >> 1) & 3)) * 8;
    #pragma unroll
    for (int t = 0; t < 6; ++t) {
        const int cur = t & 1;
        if (t + 1 < 6) {
            const int k0 = (t + 1) << 5;
            #pragma unroll
            for (int i = 0; i < 2; i++) {
                const int ch = w * 2 + i;
                gload_lds16(Ab + (size_t)(ch * 16 + sr) * K + k0 + sq,
                            &As[cur ^ 1][ch * 512 + lane * 8]);
            }
            #pragma unroll
            for (int i = 0; i < 3; i++) {
                const int ch = w * 3 + i;
                gload_lds16(BT + (size_t)(ch * 16 + sr) * K + k0 + sq,
                            &Bs[cur ^ 1][ch * 512 + lane * 8]);
            }
        }
        bf16x8 af[2];
        #pragma unroll
        for (int m = 0; m < 2; m++)
            af[m] = *reinterpret_cast<const bf16x8*>(
                &As[cur][(w * 32 + m * 16 + l16) * 32 + rdc]);
        #pragma unroll
        for (int n = 0; n < 12; n++) {
            const bf16x8 bf = *reinterpret_cast<const bf16x8*>(
                &Bs[cur][(n * 16 + l16) * 32 + rdc]);
            #pragma unroll
            for (int m = 0; m < 2; m++)
                acc[m][n] = __builtin_amdgcn_mfma_f32_16x16x32_bf16(
                    af[m], bf, acc[m][n], 0, 0, 0);
        }
        __syncthreads();
    }

    float bv[12], gv[12], bb[12];
    #pragma unroll
    for (int n = 0; n < 12; n++) {
        const int col = n * 16 + l16;
        bv[n] = bias[col]; gv[n] = g2[col]; bb[n] = b2[col];
    }

    #pragma unroll
    for (int m = 0; m < 2; m++) {
        #pragma unroll
        for (int j = 0; j < 4; j++) {
            const int row = row0 + w * 32 + m * 16 + l4 * 4 + j;   // window-token idx
            const int widx = row / 49, n49 = row - widx * 49;
            const int b = widx >> 6, win = widx & 63;
            const int wh = win >> 3, ww = win & 7;
            const int r = n49 / 7, cc = n49 - r * 7;
            int hh = wh * 7 + r + 3;  if (hh >= 56) hh -= 56;
            int wcc = ww * 7 + cc + 3; if (wcc >= 56) wcc -= 56;
            const size_t tok = ((size_t)b * 3136 + hh * 56 + wcc) * 192;
            float v[12];
            float s1 = 0.f, s2 = 0.f;
            #pragma unroll
            for (int n = 0; n < 12; n++) {
                v[n] = xres[tok + n * 16 + l16] + acc[m][n][j] + bv[n];
                s1 += v[n];
                s2 += v[n] * v[n];
            }
            #pragma unroll
            for (int off = 1; off < 16; off <<= 1) {
                s1 += __shfl_xor(s1, off, 64);
                s2 += __shfl_xor(s2, off, 64);
            }
            const float mu = s1 * (1.f / 192.f);
            const float var = s2 * (1.f / 192.f) - mu * mu;
            const float rs = rsqrtf(var + 1e-5f);
            #pragma unroll
            for (int n = 0; n < 12; n++) {
                const size_t o = tok + n * 16 + l16;
                x2[o] = v[n];
                xn[o] = f2b((v[n] - mu) * rs * gv[n] + bb[n]);
            }
        }
    }
}

// ---------- MFMA attention: one wave (64 thr) per (window, head) ----------
__global__ __launch_bounds__(64) void attn_mfma_k(
    const unsigned short* __restrict__ qkv, const float* __restrict__ rpb,
    unsigned short* __restrict__ out)
{
    const int blk = blockIdx.x;
    const int widx = blk / 6, head = blk - widx * 6;
    const int win = widx & 63;
    const int wh = win >> 3, ww = win & 7;

    __shared__ __align__(16) unsigned short vt[32 * 72];  // V^T [d][m], stride 72
    __shared__ __align__(16) unsigned short pl[64 * 72];  // P  [n][m], stride 72
    __shared__ float bias_s[256];

    const int lane = threadIdx.x;
    const int l16 = lane & 15, l4 = lane >> 4;
    const size_t base = (size_t)widx * 49 * 576 + (size_t)head * 32;

    for (int i = lane; i < 169; i += 64) bias_s[i] = rpb[i * 6 + head];

    #pragma unroll
    for (int it = 0; it < 4; ++it) {
        const int c = lane + it * 64;
        const int m = c >> 2, d8 = (c & 3) * 8;
        bf16x8 v8 = {};
        if (m < 49)
            v8 = *reinterpret_cast<const bf16x8*>(qkv + base + (size_t)m * 576 + 384 + d8);
        #pragma unroll
        for (int r = 0; r < 8; ++r) vt[(d8 + r) * 72 + m] = (unsigned short)v8[r];
    }

    bf16x8 kf[4], qf[4];
    #pragma unroll
    for (int f = 0; f < 4; ++f) {
        const int rrow = f * 16 + l16;
        bf16x8 kz = {}, qz = {};
        if (rrow < 49) {
            kz = *reinterpret_cast<const bf16x8*>(qkv + base + (size_t)rrow * 576 + 192 + l4 * 8);
            qz = *reinterpret_cast<const bf16x8*>(qkv + base + (size_t)rrow * 576 + l4 * 8);
        }
        kf[f] = kz; qf[f] = qz;
    }

    f32x4 acc[4][4];
    #pragma unroll
    for (int mf = 0; mf < 4; ++mf)
        #pragma unroll
        for (int nf = 0; nf < 4; ++nf) {
            f32x4 z = (f32x4){0.f, 0.f, 0.f, 0.f};
            acc[mf][nf] = __builtin_amdgcn_mfma_f32_16x16x32_bf16(kf[mf], qf[nf], z, 0, 0, 0);
        }

    __syncthreads();

    int gn[4], labn[4]; bool nok[4];
    #pragma unroll
    for (int nf = 0; nf < 4; ++nf) {
        const int n = nf * 16 + l16;
        const int rn = (n * 9363) >> 16, cn = n - rn * 7;
        gn[nf] = n + 6 * rn;
        labn[nf] = (wh == 7 ? (rn < 4 ? 1 : 2) : 0) * 3 + (ww == 7 ? (cn < 4 ? 1 : 2) : 0);
        nok[nf] = (n < 49);
    }

    #pragma unroll
    for (int mf = 0; mf < 4; ++mf) {
        #pragma unroll
        for (int j = 0; j < 4; ++j) {
            const int m = mf * 16 + l4 * 4 + j;
            const int rm = (m * 9363) >> 16, cm = m - rm * 7;
            const int gm = m + 6 * rm;
            const int labm = (wh == 7 ? (rm < 4 ? 1 : 2) : 0) * 3 + (ww == 7 ? (cm < 4 ? 1 : 2) : 0);
            const bool mok = (m < 49);
            #pragma unroll
            for (int nf = 0; nf < 4; ++nf) {
                float s = -1e30f;
                if (mok && nok[nf]) {
                    s = acc[mf][nf][j] * SCALE_ + bias_s[gn[nf] - gm + 84];
                    if (labn[nf] != labm) s -= 100.f;
                }
                acc[mf][nf][j] = s;
            }
        }
    }

    #pragma unroll
    for (int nf = 0; nf < 4; ++nf) {
        float mx = -1e30f;
        #pragma unroll
        for (int mf = 0; mf < 4; ++mf)
            #pragma unroll
            for (int j = 0; j < 4; ++j) mx = fmaxf(mx, acc[mf][nf][j]);
        mx = fmaxf(mx, __shfl_xor(mx, 16, 64));
        mx = fmaxf(mx, __shfl_xor(mx, 32, 64));
        float sum = 0.f;
        #pragma unroll
        for (int mf = 0; mf < 4; ++mf)
            #pragma unroll
            for (int j = 0; j < 4; ++j) {
                const float e = __expf(acc[mf][nf][j] - mx);
                acc[mf][nf][j] = e;
                sum += e;
            }
        sum += __shfl_xor(sum, 16, 64);
        sum += __shfl_xor(sum, 32, 64);
        const float inv = 1.f / sum;
        const int n = nf * 16 + l16;
        #pragma unroll
        for (int mf = 0; mf < 4; ++mf)
            #pragma unroll
            for (int jp = 0; jp < 2; ++jp) {
                const int m = mf * 16 + l4 * 4 + jp * 2;
                const unsigned int pk =
                    (unsigned int)f2b(acc[mf][nf][jp * 2] * inv) |
                    ((unsigned int)f2b(acc[mf][nf][jp * 2 + 1] * inv) << 16);
                *reinterpret_cast<unsigned int*>(&pl[n * 72 + m]) = pk;
            }
    }
    __syncthreads();

    f32x4 oacc[4][2];
    #pragma unroll
    for (int nf = 0; nf < 4; ++nf)
        #pragma unroll
        for (int df = 0; df < 2; ++df) oacc[nf][df] = (f32x4){0.f, 0.f, 0.f, 0.f};
    #pragma unroll
    for (int ks = 0; ks < 2; ++ks) {
        bf16x8 vf[2];
        #pragma unroll
        for (int df = 0; df < 2; ++df)
            vf[df] = *reinterpret_cast<const bf16x8*>(&vt[(df * 16 + l16) * 72 + ks * 32 + l4 * 8]);
        #pragma unroll
        for (int nf = 0; nf < 4; ++nf) {
            const bf16x8 pf = *reinterpret_cast<const bf16x8*>(&pl[(nf * 16 + l16) * 72 + ks * 32 + l4 * 8]);
            #pragma unroll
            for (int df = 0; df < 2; ++df)
                oacc[nf][df] = __builtin_amdgcn_mfma_f32_16x16x32_bf16(pf, vf[df], oacc[nf][df], 0, 0, 0);
        }
    }

    #pragma unroll
    for (int nf = 0; nf < 4; ++nf)
        #pragma unroll
        for (int j = 0; j < 4; ++j) {
            const int n = nf * 16 + l4 * 4 + j;
            if (n < 49) {
                const size_t o = ((size_t)widx * 49 + n) * 192 + (size_t)head * 32;
                out[o + l16]      = f2b(oacc[nf][0][j]);
                out[o + 16 + l16] = f2b(oacc[nf][1][j]);
            }
        }
}

// ---------- launch ----------
extern "C" void kernel_launch(void* const* d_in, const int* in_sizes, int n_in,
                              void* d_out, int out_size, void* d_ws, size_t ws_size,
                              hipStream_t stream)
{
    const float* x      = (const float*)d_in[0];
    const float* n1g    = (const float*)d_in[1];
    const float* n1b    = (const float*)d_in[2];
    const float* qkv_w  = (const float*)d_in[3];
    const float* qkv_b  = (const float*)d_in[4];
    const float* rpb    = (const float*)d_in[5];
    const float* proj_w = (const float*)d_in[6];
    const float* proj_b = (const float*)d_in[7];
    const float* n2g    = (const float*)d_in[8];
    const float* n2b    = (const float*)d_in[9];
    const float* fc1_w  = (const float*)d_in[10];
    const float* fc1_b  = (const float*)d_in[11];
    const float* fc2_w  = (const float*)d_in[12];
    const float* fc2_b  = (const float*)d_in[13];
    float* out = (float*)d_out;

    const int M = MTOK;  // 100352 = 784*128
    unsigned short* big   = (unsigned short*)d_ws;          // M*768
    unsigned short* winx  = big + (size_t)M * 768;          // M*192 (ln1-win, attn-out)
    unsigned short* qkvT  = winx + (size_t)M * 192;         // 576*192
    unsigned short* projT = qkvT + 576 * 192;               // 192*192
    unsigned short* fc1T  = projT + 192 * 192;              // 768*192
    unsigned short* fc2T  = fc1T + 768 * 192;               // 192*768
    unsigned short* xn    = fc2T + 192 * 768;               // M*192 (LN2 out, token order)

    // 0) weights -> bf16 transposed
    wconv_k<<<(576 * 192 + 255) / 256, 256, 0, stream>>>(qkv_w, qkvT, 192, 576);
    wconv_k<<<(192 * 192 + 255) / 256, 256, 0, stream>>>(proj_w, projT, 192, 192);
    wconv_k<<<(768 * 192 + 255) / 256, 256, 0, stream>>>(fc1_w, fc1T, 192, 768);
    wconv_k<<<(192 * 768 + 255) / 256, 256, 0, stream>>>(fc2_w, fc2T, 768, 192);

    // 1) LN1 + shift + window partition -> winx (bf16)
    ln1_window_k<<<M / 4, 256, 0, stream>>>(x, n1g, n1b, winx);
    // 2) qkv: (M,192)@(192,576) -> big
    mgemm_k<EPI_STORE_BF16><<<9 * (M / 128), 256, 0, stream>>>(
        winx, qkvT, qkv_b, big, nullptr, 576, 192, 9);
    // 3) attention (MFMA, one wave per window×head) -> winx
    attn_mfma_k<<<2048 * 6, 64, 0, stream>>>(big, rpb, winx);
    // 4) proj + window-reverse + residual + LN2 -> d_out (x2, f32) and xn (bf16)
    projln_k<<<M / 128, 256, 0, stream>>>(
        winx, projT, proj_b, x, n2g, n2b, out, xn);
    // 5) fc1 + GELU(tanh): (M,192)@(192,768) -> big
    mgemm_k<EPI_GELU><<<12 * (M / 128), 256, 0, stream>>>(
        xn, fc1T, fc1_b, big, nullptr, 768, 192, 12);
    // 6) fc2 + residual -> d_out
    mgemm_k<EPI_RES><<<3 * (M / 128), 256, 0, stream>>>(
        big, fc2T, fc2_b, nullptr, out, 192, 768, 3);
}

// Round 14
// 399.292 us; speedup vs baseline: 1.1039x; 1.0155x over previous
//
#include <hip/hip_runtime.h>
#include <hip/hip_bf16.h>
#include <math.h>

// ---------- constants ----------
// B=32, H=W=56, C=192, WS=7, SS=3, NH=6, HD=32, N=49, NW=64
#define MTOK 100352
#define SCALE_ 0.17677669529663687f

typedef short bf16x8 __attribute__((ext_vector_type(8)));
typedef float f32x4 __attribute__((ext_vector_type(4)));

__device__ __forceinline__ float b2f(unsigned short u) {
    return __uint_as_float(((unsigned int)u) << 16);
}
__device__ __forceinline__ unsigned short f2b(float f) {
    unsigned int u = __float_as_uint(f);
    unsigned int r = (u + 0x7FFFu + ((u >> 16) & 1u)) >> 16;
    return (unsigned short)r;
}
__device__ __forceinline__ void gload_lds16(const unsigned short* g, unsigned short* l) {
    __builtin_amdgcn_global_load_lds(
        (const __attribute__((address_space(1))) void*)g,
        (__attribute__((address_space(3))) void*)l, 16, 0, 0);
}

// ---------- weight convert+transpose: W[K][N] f32 -> W^T[N][K] bf16 ----------
__global__ __launch_bounds__(256) void wconv_k(
    const float* __restrict__ w, unsigned short* __restrict__ wt, int K, int N)
{
    const int i = blockIdx.x * 256 + threadIdx.x;
    if (i >= N * K) return;
    const int n = i / K, k = i - n * K;
    wt[i] = f2b(w[(size_t)k * N + n]);
}

// ---------- LN1 + cyclic shift + window partition ----------
__global__ __launch_bounds__(256) void ln1_window_k(
    const float* __restrict__ x, const float* __restrict__ g,
    const float* __restrict__ bt, unsigned short* __restrict__ out)
{
    const int wid = (blockIdx.x * 256 + threadIdx.x) >> 6;
    if (wid >= MTOK) return;
    const int lane = threadIdx.x & 63;
    const int widx = wid / 49, n = wid - widx * 49;
    const int b = widx >> 6, win = widx & 63;
    const int wh = win >> 3, ww = win & 7;
    const int r = n / 7, cc = n - r * 7;
    int hh = wh * 7 + r + 3;  if (hh >= 56) hh -= 56;
    int wc = ww * 7 + cc + 3; if (wc >= 56) wc -= 56;
    const size_t src = ((size_t)b * 3136 + hh * 56 + wc) * 192;
    const float v0 = x[src + lane], v1 = x[src + lane + 64], v2 = x[src + lane + 128];
    float s1 = v0 + v1 + v2;
    float s2 = v0 * v0 + v1 * v1 + v2 * v2;
    #pragma unroll
    for (int off = 32; off; off >>= 1) {
        s1 += __shfl_xor(s1, off, 64);
        s2 += __shfl_xor(s2, off, 64);
    }
    const float mu = s1 * (1.f / 192.f);
    const float var = s2 * (1.f / 192.f) - mu * mu;
    const float rs = rsqrtf(var + 1e-5f);
    const size_t dst = (size_t)wid * 192;
    out[dst + lane]       = f2b((v0 - mu) * rs * g[lane]       + bt[lane]);
    out[dst + lane + 64]  = f2b((v1 - mu) * rs * g[lane + 64]  + bt[lane + 64]);
    out[dst + lane + 128] = f2b((v2 - mu) * rs * g[lane + 128] + bt[lane + 128]);
}

// ---------- LN2 (token-order) ----------
__global__ __launch_bounds__(256) void ln2_k(
    const float* __restrict__ x, const float* __restrict__ g,
    const float* __restrict__ bt, unsigned short* __restrict__ out)
{
    const int t = (blockIdx.x * 256 + threadIdx.x) >> 6;
    if (t >= MTOK) return;
    const int lane = threadIdx.x & 63;
    const size_t src = (size_t)t * 192;
    const float v0 = x[src + lane], v1 = x[src + lane + 64], v2 = x[src + lane + 128];
    float s1 = v0 + v1 + v2;
    float s2 = v0 * v0 + v1 * v1 + v2 * v2;
    #pragma unroll
    for (int off = 32; off; off >>= 1) {
        s1 += __shfl_xor(s1, off, 64);
        s2 += __shfl_xor(s2, off, 64);
    }
    const float mu = s1 * (1.f / 192.f);
    const float var = s2 * (1.f / 192.f) - mu * mu;
    const float rs = rsqrtf(var + 1e-5f);
    out[src + lane]       = f2b((v0 - mu) * rs * g[lane]       + bt[lane]);
    out[src + lane + 64]  = f2b((v1 - mu) * rs * g[lane + 64]  + bt[lane + 64]);
    out[src + lane + 128] = f2b((v2 - mu) * rs * g[lane + 128] + bt[lane + 128]);
}

// ---------- MFMA GEMM, full-K LDS residency ----------
// C[M,N] = A[M,K](bf16) @ W^T[N][K](bf16). tile 128x64, 4 waves in 2x2,
// each wave 64x32 (4x2 frags). Per 192-col chunk: stage A(128x192)+B(64x192)
// = 72 KB LDS with 18 gload_lds16/wave, ONE barrier, then 6 K-steps of pure
// ds_read+MFMA with NO barriers (K=192: 1 drain/block; K=768: 4 chunks).
// Per-subchunk layout identical to the verified R10 swizzle:
//   dest [ks*stride + ch*512 + lane*8], source col ((lane&3)^((lane>>3)&3))*8,
//   read col (l4^((l16>>1)&3))*8 -> 0 bank conflicts (R10 counter-verified).
enum { EPI_STORE_BF16 = 0, EPI_PROJ = 1, EPI_GELU = 2, EPI_RES = 3 };

template <int EPI, int K>
__global__ __launch_bounds__(256) void mgemm_k(
    const unsigned short* __restrict__ A, const unsigned short* __restrict__ BT,
    const float* __restrict__ bias, unsigned short* __restrict__ outb,
    float* __restrict__ outf, const float* __restrict__ xres,
    int N, int gx)
{
    constexpr int NKC = K / 192;   // 192-col chunks
    __shared__ __align__(16) unsigned short As[128 * 192];  // 48 KB
    __shared__ __align__(16) unsigned short Bs[64 * 192];   // 24 KB

    const int nwg = gridDim.x;
    int lin = blockIdx.x;
    lin = (lin & 7) * (nwg >> 3) + (lin >> 3);
    const int bn = lin % gx, bm = lin / gx;
    const int row0 = bm * 128, col0 = bn * 64;

    const int tid = threadIdx.x;
    const int w = tid >> 6, lane = tid & 63;
    const int wr = w >> 1, wc = w & 1;
    const int l16 = lane & 15, l4 = lane >> 4;

    const unsigned short* Ab = A + (size_t)row0 * K;
    const unsigned short* Bb = BT + (size_t)col0 * K;
    const int sr = lane >> 2;
    const int sq = ((lane & 3) ^ ((lane >> 3) & 3)) * 8;
    const int rdc = (l4 ^ ((l16 >> 1) & 3)) * 8;

    f32x4 acc[4][2];
    #pragma unroll
    for (int m = 0; m < 4; m++)
        #pragma unroll
        for (int n = 0; n < 2; n++) acc[m][n] = (f32x4){0.f, 0.f, 0.f, 0.f};

    for (int kc = 0; kc < NKC; ++kc) {
        const int kbase = kc * 192;
        if (kc) __syncthreads();          // prior chunk fully consumed
        // stage A: 48 gloads (12/wave): idx -> ks (subchunk), ch (16-row group)
        #pragma unroll
        for (int i = 0; i < 12; i++) {
            const int idx = w * 12 + i;
            const int ks = idx >> 3, ch = idx & 7;
            gload_lds16(Ab + (size_t)(ch * 16 + sr) * K + kbase + ks * 32 + sq,
                        &As[ks * 4096 + ch * 512 + lane * 8]);
        }
        // stage B: 24 gloads (6/wave)
        #pragma unroll
        for (int i = 0; i < 6; i++) {
            const int idx = w * 6 + i;
            const int ks = idx >> 2, rg = idx & 3;
            gload_lds16(Bb + (size_t)(rg * 16 + sr) * K + kbase + ks * 32 + sq,
                        &Bs[ks * 2048 + rg * 512 + lane * 8]);
        }
        __syncthreads();                  // the ONLY drain for this chunk
        #pragma unroll
        for (int ks = 0; ks < 6; ++ks) {
            bf16x8 af[4], bf[2];
            #pragma unroll
            for (int m = 0; m < 4; m++)
                af[m] = *reinterpret_cast<const bf16x8*>(
                    &As[ks * 4096 + (wr * 64 + m * 16 + l16) * 32 + rdc]);
            #pragma unroll
            for (int n = 0; n < 2; n++)
                bf[n] = *reinterpret_cast<const bf16x8*>(
                    &Bs[ks * 2048 + (wc * 32 + n * 16 + l16) * 32 + rdc]);
            #pragma unroll
            for (int m = 0; m < 4; m++)
                #pragma unroll
                for (int n = 0; n < 2; n++)
                    acc[m][n] = __builtin_amdgcn_mfma_f32_16x16x32_bf16(
                        af[m], bf[n], acc[m][n], 0, 0, 0);
        }
    }

    float bv[2];
    #pragma unroll
    for (int n = 0; n < 2; n++) bv[n] = bias[col0 + wc * 32 + n * 16 + l16];

    #pragma unroll
    for (int m = 0; m < 4; m++) {
        #pragma unroll
        for (int j = 0; j < 4; j++) {
            const int row = row0 + wr * 64 + m * 16 + l4 * 4 + j;
            if constexpr (EPI == EPI_PROJ) {
                const int widx = row / 49, n49 = row - widx * 49;
                const int b = widx >> 6, win = widx & 63;
                const int wh = win >> 3, ww = win & 7;
                const int r = n49 / 7, cc = n49 - r * 7;
                int hh = wh * 7 + r + 3;  if (hh >= 56) hh -= 56;
                int wcc = ww * 7 + cc + 3; if (wcc >= 56) wcc -= 56;
                const size_t tok = ((size_t)b * 3136 + hh * 56 + wcc) * 192;
                #pragma unroll
                for (int n = 0; n < 2; n++) {
                    const int col = col0 + wc * 32 + n * 16 + l16;
                    outf[tok + col] = xres[tok + col] + acc[m][n][j] + bv[n];
                }
            } else if constexpr (EPI == EPI_STORE_BF16) {
                #pragma unroll
                for (int n = 0; n < 2; n++) {
                    const int col = col0 + wc * 32 + n * 16 + l16;
                    outb[(size_t)row * N + col] = f2b(acc[m][n][j] + bv[n]);
                }
            } else if constexpr (EPI == EPI_GELU) {
                #pragma unroll
                for (int n = 0; n < 2; n++) {
                    const int col = col0 + wc * 32 + n * 16 + l16;
                    float v = acc[m][n][j] + bv[n];
                    // tanh-form GELU via sigmoid + fast rcp/exp (|err|<=3e-3)
                    const float wv = v + 0.044715f * v * v * v;
                    const float sg = __builtin_amdgcn_rcpf(
                        1.f + __expf(-1.5957691216057308f * wv));
                    v = v * sg;
                    outb[(size_t)row * N + col] = f2b(v);
                }
            } else {  // EPI_RES
                #pragma unroll
                for (int n = 0; n < 2; n++) {
                    const int col = col0 + wc * 32 + n * 16 + l16;
                    outf[(size_t)row * N + col] += acc[m][n][j] + bv[n];
                }
            }
        }
    }
}

// ---------- MFMA attention: one wave (64 thr) per (window, head) ----------
__global__ __launch_bounds__(64) void attn_mfma_k(
    const unsigned short* __restrict__ qkv, const float* __restrict__ rpb,
    unsigned short* __restrict__ out)
{
    const int blk = blockIdx.x;
    const int widx = blk / 6, head = blk - widx * 6;
    const int win = widx & 63;
    const int wh = win >> 3, ww = win & 7;

    __shared__ __align__(16) unsigned short vt[32 * 72];  // V^T [d][m], stride 72
    __shared__ __align__(16) unsigned short pl[64 * 72];  // P  [n][m], stride 72
    __shared__ float bias_s[256];

    const int lane = threadIdx.x;
    const int l16 = lane & 15, l4 = lane >> 4;
    const size_t base = (size_t)widx * 49 * 576 + (size_t)head * 32;

    for (int i = lane; i < 169; i += 64) bias_s[i] = rpb[i * 6 + head];

    #pragma unroll
    for (int it = 0; it < 4; ++it) {
        const int c = lane + it * 64;
        const int m = c >> 2, d8 = (c & 3) * 8;
        bf16x8 v8 = {};
        if (m < 49)
            v8 = *reinterpret_cast<const bf16x8*>(qkv + base + (size_t)m * 576 + 384 + d8);
        #pragma unroll
        for (int r = 0; r < 8; ++r) vt[(d8 + r) * 72 + m] = (unsigned short)v8[r];
    }

    bf16x8 kf[4], qf[4];
    #pragma unroll
    for (int f = 0; f < 4; ++f) {
        const int rrow = f * 16 + l16;
        bf16x8 kz = {}, qz = {};
        if (rrow < 49) {
            kz = *reinterpret_cast<const bf16x8*>(qkv + base + (size_t)rrow * 576 + 192 + l4 * 8);
            qz = *reinterpret_cast<const bf16x8*>(qkv + base + (size_t)rrow * 576 + l4 * 8);
        }
        kf[f] = kz; qf[f] = qz;
    }

    f32x4 acc[4][4];
    #pragma unroll
    for (int mf = 0; mf < 4; ++mf)
        #pragma unroll
        for (int nf = 0; nf < 4; ++nf) {
            f32x4 z = (f32x4){0.f, 0.f, 0.f, 0.f};
            acc[mf][nf] = __builtin_amdgcn_mfma_f32_16x16x32_bf16(kf[mf], qf[nf], z, 0, 0, 0);
        }

    __syncthreads();

    int gn[4], labn[4]; bool nok[4];
    #pragma unroll
    for (int nf = 0; nf < 4; ++nf) {
        const int n = nf * 16 + l16;
        const int rn = (n * 9363) >> 16, cn = n - rn * 7;
        gn[nf] = n + 6 * rn;
        labn[nf] = (wh == 7 ? (rn < 4 ? 1 : 2) : 0) * 3 + (ww == 7 ? (cn < 4 ? 1 : 2) : 0);
        nok[nf] = (n < 49);
    }

    #pragma unroll
    for (int mf = 0; mf < 4; ++mf) {
        #pragma unroll
        for (int j = 0; j < 4; ++j) {
            const int m = mf * 16 + l4 * 4 + j;
            const int rm = (m * 9363) >> 16, cm = m - rm * 7;
            const int gm = m + 6 * rm;
            const int labm = (wh == 7 ? (rm < 4 ? 1 : 2) : 0) * 3 + (ww == 7 ? (cm < 4 ? 1 : 2) : 0);
            const bool mok = (m < 49);
            #pragma unroll
            for (int nf = 0; nf < 4; ++nf) {
                float s = -1e30f;
                if (mok && nok[nf]) {
                    s = acc[mf][nf][j] * SCALE_ + bias_s[gn[nf] - gm + 84];
                    if (labn[nf] != labm) s -= 100.f;
                }
                acc[mf][nf][j] = s;
            }
        }
    }

    #pragma unroll
    for (int nf = 0; nf < 4; ++nf) {
        float mx = -1e30f;
        #pragma unroll
        for (int mf = 0; mf < 4; ++mf)
            #pragma unroll
            for (int j = 0; j < 4; ++j) mx = fmaxf(mx, acc[mf][nf][j]);
        mx = fmaxf(mx, __shfl_xor(mx, 16, 64));
        mx = fmaxf(mx, __shfl_xor(mx, 32, 64));
        float sum = 0.f;
        #pragma unroll
        for (int mf = 0; mf < 4; ++mf)
            #pragma unroll
            for (int j = 0; j < 4; ++j) {
                const float e = __expf(acc[mf][nf][j] - mx);
                acc[mf][nf][j] = e;
                sum += e;
            }
        sum += __shfl_xor(sum, 16, 64);
        sum += __shfl_xor(sum, 32, 64);
        const float inv = 1.f / sum;
        const int n = nf * 16 + l16;
        #pragma unroll
        for (int mf = 0; mf < 4; ++mf)
            #pragma unroll
            for (int jp = 0; jp < 2; ++jp) {
                const int m = mf * 16 + l4 * 4 + jp * 2;
                const unsigned int pk =
                    (unsigned int)f2b(acc[mf][nf][jp * 2] * inv) |
                    ((unsigned int)f2b(acc[mf][nf][jp * 2 + 1] * inv) << 16);
                *reinterpret_cast<unsigned int*>(&pl[n * 72 + m]) = pk;
            }
    }
    __syncthreads();

    f32x4 oacc[4][2];
    #pragma unroll
    for (int nf = 0; nf < 4; ++nf)
        #pragma unroll
        for (int df = 0; df < 2; ++df) oacc[nf][df] = (f32x4){0.f, 0.f, 0.f, 0.f};
    #pragma unroll
    for (int ks = 0; ks < 2; ++ks) {
        bf16x8 vf[2];
        #pragma unroll
        for (int df = 0; df < 2; ++df)
            vf[df] = *reinterpret_cast<const bf16x8*>(&vt[(df * 16 + l16) * 72 + ks * 32 + l4 * 8]);
        #pragma unroll
        for (int nf = 0; nf < 4; ++nf) {
            const bf16x8 pf = *reinterpret_cast<const bf16x8*>(&pl[(nf * 16 + l16) * 72 + ks * 32 + l4 * 8]);
            #pragma unroll
            for (int df = 0; df < 2; ++df)
                oacc[nf][df] = __builtin_amdgcn_mfma_f32_16x16x32_bf16(pf, vf[df], oacc[nf][df], 0, 0, 0);
        }
    }

    #pragma unroll
    for (int nf = 0; nf < 4; ++nf)
        #pragma unroll
        for (int j = 0; j < 4; ++j) {
            const int n = nf * 16 + l4 * 4 + j;
            if (n < 49) {
                const size_t o = ((size_t)widx * 49 + n) * 192 + (size_t)head * 32;
                out[o + l16]      = f2b(oacc[nf][0][j]);
                out[o + 16 + l16] = f2b(oacc[nf][1][j]);
            }
        }
}

// ---------- launch ----------
extern "C" void kernel_launch(void* const* d_in, const int* in_sizes, int n_in,
                              void* d_out, int out_size, void* d_ws, size_t ws_size,
                              hipStream_t stream)
{
    const float* x      = (const float*)d_in[0];
    const float* n1g    = (const float*)d_in[1];
    const float* n1b    = (const float*)d_in[2];
    const float* qkv_w  = (const float*)d_in[3];
    const float* qkv_b  = (const float*)d_in[4];
    const float* rpb    = (const float*)d_in[5];
    const float* proj_w = (const float*)d_in[6];
    const float* proj_b = (const float*)d_in[7];
    const float* n2g    = (const float*)d_in[8];
    const float* n2b    = (const float*)d_in[9];
    const float* fc1_w  = (const float*)d_in[10];
    const float* fc1_b  = (const float*)d_in[11];
    const float* fc2_w  = (const float*)d_in[12];
    const float* fc2_b  = (const float*)d_in[13];
    float* out = (float*)d_out;

    const int M = MTOK;  // 100352 = 784*128
    unsigned short* big   = (unsigned short*)d_ws;          // M*768
    unsigned short* winx  = big + (size_t)M * 768;          // M*192 (ln1-win, attn-out, ln2-out)
    unsigned short* qkvT  = winx + (size_t)M * 192;         // 576*192
    unsigned short* projT = qkvT + 576 * 192;               // 192*192
    unsigned short* fc1T  = projT + 192 * 192;              // 768*192
    unsigned short* fc2T  = fc1T + 768 * 192;               // 192*768

    // 0) weights -> bf16 transposed
    wconv_k<<<(576 * 192 + 255) / 256, 256, 0, stream>>>(qkv_w, qkvT, 192, 576);
    wconv_k<<<(192 * 192 + 255) / 256, 256, 0, stream>>>(proj_w, projT, 192, 192);
    wconv_k<<<(768 * 192 + 255) / 256, 256, 0, stream>>>(fc1_w, fc1T, 192, 768);
    wconv_k<<<(192 * 768 + 255) / 256, 256, 0, stream>>>(fc2_w, fc2T, 768, 192);

    // 1) LN1 + shift + window partition -> winx (bf16)
    ln1_window_k<<<M / 4, 256, 0, stream>>>(x, n1g, n1b, winx);
    // 2) qkv: (M,192)@(192,576) -> big
    mgemm_k<EPI_STORE_BF16, 192><<<9 * (M / 128), 256, 0, stream>>>(
        winx, qkvT, qkv_b, big, nullptr, nullptr, 576, 9);
    // 3) attention (MFMA, one wave per window×head) -> winx
    attn_mfma_k<<<2048 * 6, 64, 0, stream>>>(big, rpb, winx);
    // 4) proj + window-reverse + unshift + residual -> d_out (f32)
    mgemm_k<EPI_PROJ, 192><<<3 * (M / 128), 256, 0, stream>>>(
        winx, projT, proj_b, nullptr, out, x, 192, 3);
    // 5) LN2 -> winx (bf16)
    ln2_k<<<M / 4, 256, 0, stream>>>(out, n2g, n2b, winx);
    // 6) fc1 + GELU -> big
    mgemm_k<EPI_GELU, 192><<<12 * (M / 128), 256, 0, stream>>>(
        winx, fc1T, fc1_b, big, nullptr, nullptr, 768, 12);
    // 7) fc2 + residual -> d_out
    mgemm_k<EPI_RES, 768><<<3 * (M / 128), 256, 0, stream>>>(
        big, fc2T, fc2_b, nullptr, out, nullptr, 192, 3);
}

// Round 15
// 369.804 us; speedup vs baseline: 1.1919x; 1.0797x over previous
//
#include <hip/hip_runtime.h>
#include <hip/hip_bf16.h>
#include <math.h>

// ---------- constants ----------
// B=32, H=W=56, C=192, WS=7, SS=3, NH=6, HD=32, N=49, NW=64
#define MTOK 100352
#define SCALE_ 0.17677669529663687f

typedef short bf16x8 __attribute__((ext_vector_type(8)));
typedef float f32x4 __attribute__((ext_vector_type(4)));

__device__ __forceinline__ float b2f(unsigned short u) {
    return __uint_as_float(((unsigned int)u) << 16);
}
__device__ __forceinline__ unsigned short f2b(float f) {
    unsigned int u = __float_as_uint(f);
    unsigned int r = (u + 0x7FFFu + ((u >> 16) & 1u)) >> 16;
    return (unsigned short)r;
}
__device__ __forceinline__ void gload_lds16(const unsigned short* g, unsigned short* l) {
    __builtin_amdgcn_global_load_lds(
        (const __attribute__((address_space(1))) void*)g,
        (__attribute__((address_space(3))) void*)l, 16, 0, 0);
}

// ---------- weight convert+transpose: W[K][N] f32 -> W^T[N][K] bf16 ----------
__global__ __launch_bounds__(256) void wconv_k(
    const float* __restrict__ w, unsigned short* __restrict__ wt, int K, int N)
{
    const int i = blockIdx.x * 256 + threadIdx.x;
    if (i >= N * K) return;
    const int n = i / K, k = i - n * K;
    wt[i] = f2b(w[(size_t)k * N + n]);
}

// ---------- LN1 + cyclic shift + window partition ----------
__global__ __launch_bounds__(256) void ln1_window_k(
    const float* __restrict__ x, const float* __restrict__ g,
    const float* __restrict__ bt, unsigned short* __restrict__ out)
{
    const int wid = (blockIdx.x * 256 + threadIdx.x) >> 6;
    if (wid >= MTOK) return;
    const int lane = threadIdx.x & 63;
    const int widx = wid / 49, n = wid - widx * 49;
    const int b = widx >> 6, win = widx & 63;
    const int wh = win >> 3, ww = win & 7;
    const int r = n / 7, cc = n - r * 7;
    int hh = wh * 7 + r + 3;  if (hh >= 56) hh -= 56;
    int wc = ww * 7 + cc + 3; if (wc >= 56) wc -= 56;
    const size_t src = ((size_t)b * 3136 + hh * 56 + wc) * 192;
    const float v0 = x[src + lane], v1 = x[src + lane + 64], v2 = x[src + lane + 128];
    float s1 = v0 + v1 + v2;
    float s2 = v0 * v0 + v1 * v1 + v2 * v2;
    #pragma unroll
    for (int off = 32; off; off >>= 1) {
        s1 += __shfl_xor(s1, off, 64);
        s2 += __shfl_xor(s2, off, 64);
    }
    const float mu = s1 * (1.f / 192.f);
    const float var = s2 * (1.f / 192.f) - mu * mu;
    const float rs = rsqrtf(var + 1e-5f);
    const size_t dst = (size_t)wid * 192;
    out[dst + lane]       = f2b((v0 - mu) * rs * g[lane]       + bt[lane]);
    out[dst + lane + 64]  = f2b((v1 - mu) * rs * g[lane + 64]  + bt[lane + 64]);
    out[dst + lane + 128] = f2b((v2 - mu) * rs * g[lane + 128] + bt[lane + 128]);
}

// ---------- LN2 (token-order) ----------
__global__ __launch_bounds__(256) void ln2_k(
    const float* __restrict__ x, const float* __restrict__ g,
    const float* __restrict__ bt, unsigned short* __restrict__ out)
{
    const int t = (blockIdx.x * 256 + threadIdx.x) >> 6;
    if (t >= MTOK) return;
    const int lane = threadIdx.x & 63;
    const size_t src = (size_t)t * 192;
    const float v0 = x[src + lane], v1 = x[src + lane + 64], v2 = x[src + lane + 128];
    float s1 = v0 + v1 + v2;
    float s2 = v0 * v0 + v1 * v1 + v2 * v2;
    #pragma unroll
    for (int off = 32; off; off >>= 1) {
        s1 += __shfl_xor(s1, off, 64);
        s2 += __shfl_xor(s2, off, 64);
    }
    const float mu = s1 * (1.f / 192.f);
    const float var = s2 * (1.f / 192.f) - mu * mu;
    const float rs = rsqrtf(var + 1e-5f);
    out[src + lane]       = f2b((v0 - mu) * rs * g[lane]       + bt[lane]);
    out[src + lane + 64]  = f2b((v1 - mu) * rs * g[lane + 64]  + bt[lane + 64]);
    out[src + lane + 128] = f2b((v2 - mu) * rs * g[lane + 128] + bt[lane + 128]);
}

// ---------- MFMA GEMM (R10 structure + counted-vmcnt pipeline) ----------
// C[M,N] = A[M,K](bf16) @ W^T[N][K](bf16). tile 128x64, BK=32, dbuf 24 KB.
// K-loop sync: raw s_barrier + s_waitcnt vmcnt(3) — tile t+1's 3 global_load_lds
// stay IN FLIGHT across the barrier (never drain to 0 until the last step).
// Swizzle (verified R10, 0 conflicts): source col ((lane&3)^((lane>>3)&3))*8,
// read col (l4^((l16>>1)&3))*8.
enum { EPI_STORE_BF16 = 0, EPI_PROJ = 1, EPI_GELU = 2, EPI_RES = 3 };

template <int EPI>
__global__ __launch_bounds__(256) void mgemm_k(
    const unsigned short* __restrict__ A, const unsigned short* __restrict__ BT,
    const float* __restrict__ bias, unsigned short* __restrict__ outb,
    float* __restrict__ outf, const float* __restrict__ xres,
    int N, int K, int gx)
{
    __shared__ __align__(16) unsigned short As[2][128 * 32];  // 2x8 KB
    __shared__ __align__(16) unsigned short Bs[2][64 * 32];   // 2x4 KB

    const int nwg = gridDim.x;
    int lin = blockIdx.x;
    lin = (lin & 7) * (nwg >> 3) + (lin >> 3);
    const int bn = lin % gx, bm = lin / gx;
    const int row0 = bm * 128, col0 = bn * 64;

    const int tid = threadIdx.x;
    const int w = tid >> 6, lane = tid & 63;
    const int wr = w >> 1, wc = w & 1;
    const int l16 = lane & 15, l4 = lane >> 4;

    const unsigned short* Ab = A + (size_t)row0 * K;
    const unsigned short* Bb = BT + (size_t)col0 * K;
    const int sr = lane >> 2;
    const int sq = ((lane & 3) ^ ((lane >> 3) & 3)) * 8;

    // prologue: stage tiles 0 and 1 (6 loads/thread in flight)
    #pragma unroll
    for (int i = 0; i < 2; i++) {
        const int ch = w * 2 + i;
        gload_lds16(Ab + (size_t)(ch * 16 + sr) * K + sq, &As[0][ch * 512 + lane * 8]);
    }
    gload_lds16(Bb + (size_t)(w * 16 + sr) * K + sq, &Bs[0][w * 512 + lane * 8]);
    const int nt = K >> 5;
    if (nt > 1) {
        #pragma unroll
        for (int i = 0; i < 2; i++) {
            const int ch = w * 2 + i;
            gload_lds16(Ab + (size_t)(ch * 16 + sr) * K + 32 + sq, &As[1][ch * 512 + lane * 8]);
        }
        gload_lds16(Bb + (size_t)(w * 16 + sr) * K + 32 + sq, &Bs[1][w * 512 + lane * 8]);
    }

    f32x4 acc[4][2];
    #pragma unroll
    for (int m = 0; m < 4; m++)
        #pragma unroll
        for (int n = 0; n < 2; n++) acc[m][n] = (f32x4){0.f, 0.f, 0.f, 0.f};

    const int rdc = (l4 ^ ((l16 >> 1) & 3)) * 8;
    for (int t = 0; t < nt; ++t) {
        const int cur = t & 1;
        // wait for tile t only; tile t+1's 3 loads stay in flight
        if (t + 1 < nt) asm volatile("s_waitcnt vmcnt(3)" ::: "memory");
        else            asm volatile("s_waitcnt vmcnt(0)" ::: "memory");
        __builtin_amdgcn_s_barrier();
        __builtin_amdgcn_sched_barrier(0);   // keep ds_reads below the barrier
        bf16x8 af[4], bf[2];
        #pragma unroll
        for (int m = 0; m < 4; m++)
            af[m] = *reinterpret_cast<const bf16x8*>(
                &As[cur][(wr * 64 + m * 16 + l16) * 32 + rdc]);
        #pragma unroll
        for (int n = 0; n < 2; n++)
            bf[n] = *reinterpret_cast<const bf16x8*>(
                &Bs[cur][(wc * 32 + n * 16 + l16) * 32 + rdc]);
        #pragma unroll
        for (int m = 0; m < 4; m++)
            #pragma unroll
            for (int n = 0; n < 2; n++)
                acc[m][n] = __builtin_amdgcn_mfma_f32_16x16x32_bf16(
                    af[m], bf[n], acc[m][n], 0, 0, 0);
        __builtin_amdgcn_sched_barrier(0);   // all reads of buf[cur] issued above
        __builtin_amdgcn_s_barrier();        // all waves done reading buf[cur]
        if (t + 2 < nt) {
            const int k0 = (t + 2) << 5;
            #pragma unroll
            for (int i = 0; i < 2; i++) {
                const int ch = w * 2 + i;
                gload_lds16(Ab + (size_t)(ch * 16 + sr) * K + k0 + sq,
                            &As[cur][ch * 512 + lane * 8]);
            }
            gload_lds16(Bb + (size_t)(w * 16 + sr) * K + k0 + sq,
                        &Bs[cur][w * 512 + lane * 8]);
        }
    }

    float bv[2];
    #pragma unroll
    for (int n = 0; n < 2; n++) bv[n] = bias[col0 + wc * 32 + n * 16 + l16];

    #pragma unroll
    for (int m = 0; m < 4; m++) {
        #pragma unroll
        for (int j = 0; j < 4; j++) {
            const int row = row0 + wr * 64 + m * 16 + l4 * 4 + j;
            if constexpr (EPI == EPI_PROJ) {
                const int widx = row / 49, n49 = row - widx * 49;
                const int b = widx >> 6, win = widx & 63;
                const int wh = win >> 3, ww = win & 7;
                const int r = n49 / 7, cc = n49 - r * 7;
                int hh = wh * 7 + r + 3;  if (hh >= 56) hh -= 56;
                int wcc = ww * 7 + cc + 3; if (wcc >= 56) wcc -= 56;
                const size_t tok = ((size_t)b * 3136 + hh * 56 + wcc) * 192;
                #pragma unroll
                for (int n = 0; n < 2; n++) {
                    const int col = col0 + wc * 32 + n * 16 + l16;
                    outf[tok + col] = xres[tok + col] + acc[m][n][j] + bv[n];
                }
            } else if constexpr (EPI == EPI_STORE_BF16) {
                #pragma unroll
                for (int n = 0; n < 2; n++) {
                    const int col = col0 + wc * 32 + n * 16 + l16;
                    outb[(size_t)row * N + col] = f2b(acc[m][n][j] + bv[n]);
                }
            } else if constexpr (EPI == EPI_GELU) {
                #pragma unroll
                for (int n = 0; n < 2; n++) {
                    const int col = col0 + wc * 32 + n * 16 + l16;
                    float v = acc[m][n][j] + bv[n];
                    const float wv = v + 0.044715f * v * v * v;
                    const float sg = __builtin_amdgcn_rcpf(
                        1.f + __expf(-1.5957691216057308f * wv));
                    v = v * sg;
                    outb[(size_t)row * N + col] = f2b(v);
                }
            } else {  // EPI_RES
                #pragma unroll
                for (int n = 0; n < 2; n++) {
                    const int col = col0 + wc * 32 + n * 16 + l16;
                    outf[(size_t)row * N + col] += acc[m][n][j] + bv[n];
                }
            }
        }
    }
}

// ---------- MFMA attention: one wave (64 thr) per (window, head) ----------
__global__ __launch_bounds__(64) void attn_mfma_k(
    const unsigned short* __restrict__ qkv, const float* __restrict__ rpb,
    unsigned short* __restrict__ out)
{
    const int blk = blockIdx.x;
    const int widx = blk / 6, head = blk - widx * 6;
    const int win = widx & 63;
    const int wh = win >> 3, ww = win & 7;

    __shared__ __align__(16) unsigned short vt[32 * 72];  // V^T [d][m], stride 72
    __shared__ __align__(16) unsigned short pl[64 * 72];  // P  [n][m], stride 72
    __shared__ float bias_s[256];

    const int lane = threadIdx.x;
    const int l16 = lane & 15, l4 = lane >> 4;
    const size_t base = (size_t)widx * 49 * 576 + (size_t)head * 32;

    for (int i = lane; i < 169; i += 64) bias_s[i] = rpb[i * 6 + head];

    #pragma unroll
    for (int it = 0; it < 4; ++it) {
        const int c = lane + it * 64;
        const int m = c >> 2, d8 = (c & 3) * 8;
        bf16x8 v8 = {};
        if (m < 49)
            v8 = *reinterpret_cast<const bf16x8*>(qkv + base + (size_t)m * 576 + 384 + d8);
        #pragma unroll
        for (int r = 0; r < 8; ++r) vt[(d8 + r) * 72 + m] = (unsigned short)v8[r];
    }

    bf16x8 kf[4], qf[4];
    #pragma unroll
    for (int f = 0; f < 4; ++f) {
        const int rrow = f * 16 + l16;
        bf16x8 kz = {}, qz = {};
        if (rrow < 49) {
            kz = *reinterpret_cast<const bf16x8*>(qkv + base + (size_t)rrow * 576 + 192 + l4 * 8);
            qz = *reinterpret_cast<const bf16x8*>(qkv + base + (size_t)rrow * 576 + l4 * 8);
        }
        kf[f] = kz; qf[f] = qz;
    }

    f32x4 acc[4][4];
    #pragma unroll
    for (int mf = 0; mf < 4; ++mf)
        #pragma unroll
        for (int nf = 0; nf < 4; ++nf) {
            f32x4 z = (f32x4){0.f, 0.f, 0.f, 0.f};
            acc[mf][nf] = __builtin_amdgcn_mfma_f32_16x16x32_bf16(kf[mf], qf[nf], z, 0, 0, 0);
        }

    __syncthreads();

    int gn[4], labn[4]; bool nok[4];
    #pragma unroll
    for (int nf = 0; nf < 4; ++nf) {
        const int n = nf * 16 + l16;
        const int rn = (n * 9363) >> 16, cn = n - rn * 7;
        gn[nf] = n + 6 * rn;
        labn[nf] = (wh == 7 ? (rn < 4 ? 1 : 2) : 0) * 3 + (ww == 7 ? (cn < 4 ? 1 : 2) : 0);
        nok[nf] = (n < 49);
    }

    #pragma unroll
    for (int mf = 0; mf < 4; ++mf) {
        #pragma unroll
        for (int j = 0; j < 4; ++j) {
            const int m = mf * 16 + l4 * 4 + j;
            const int rm = (m * 9363) >> 16, cm = m - rm * 7;
            const int gm = m + 6 * rm;
            const int labm = (wh == 7 ? (rm < 4 ? 1 : 2) : 0) * 3 + (ww == 7 ? (cm < 4 ? 1 : 2) : 0);
            const bool mok = (m < 49);
            #pragma unroll
            for (int nf = 0; nf < 4; ++nf) {
                float s = -1e30f;
                if (mok && nok[nf]) {
                    s = acc[mf][nf][j] * SCALE_ + bias_s[gn[nf] - gm + 84];
                    if (labn[nf] != labm) s -= 100.f;
                }
                acc[mf][nf][j] = s;
            }
        }
    }

    #pragma unroll
    for (int nf = 0; nf < 4; ++nf) {
        float mx = -1e30f;
        #pragma unroll
        for (int mf = 0; mf < 4; ++mf)
            #pragma unroll
            for (int j = 0; j < 4; ++j) mx = fmaxf(mx, acc[mf][nf][j]);
        mx = fmaxf(mx, __shfl_xor(mx, 16, 64));
        mx = fmaxf(mx, __shfl_xor(mx, 32, 64));
        float sum = 0.f;
        #pragma unroll
        for (int mf = 0; mf < 4; ++mf)
            #pragma unroll
            for (int j = 0; j < 4; ++j) {
                const float e = __expf(acc[mf][nf][j] - mx);
                acc[mf][nf][j] = e;
                sum += e;
            }
        sum += __shfl_xor(sum, 16, 64);
        sum += __shfl_xor(sum, 32, 64);
        const float inv = 1.f / sum;
        const int n = nf * 16 + l16;
        #pragma unroll
        for (int mf = 0; mf < 4; ++mf)
            #pragma unroll
            for (int jp = 0; jp < 2; ++jp) {
                const int m = mf * 16 + l4 * 4 + jp * 2;
                const unsigned int pk =
                    (unsigned int)f2b(acc[mf][nf][jp * 2] * inv) |
                    ((unsigned int)f2b(acc[mf][nf][jp * 2 + 1] * inv) << 16);
                *reinterpret_cast<unsigned int*>(&pl[n * 72 + m]) = pk;
            }
    }
    __syncthreads();

    f32x4 oacc[4][2];
    #pragma unroll
    for (int nf = 0; nf < 4; ++nf)
        #pragma unroll
        for (int df = 0; df < 2; ++df) oacc[nf][df] = (f32x4){0.f, 0.f, 0.f, 0.f};
    #pragma unroll
    for (int ks = 0; ks < 2; ++ks) {
        bf16x8 vf[2];
        #pragma unroll
        for (int df = 0; df < 2; ++df)
            vf[df] = *reinterpret_cast<const bf16x8*>(&vt[(df * 16 + l16) * 72 + ks * 32 + l4 * 8]);
        #pragma unroll
        for (int nf = 0; nf < 4; ++nf) {
            const bf16x8 pf = *reinterpret_cast<const bf16x8*>(&pl[(nf * 16 + l16) * 72 + ks * 32 + l4 * 8]);
            #pragma unroll
            for (int df = 0; df < 2; ++df)
                oacc[nf][df] = __builtin_amdgcn_mfma_f32_16x16x32_bf16(pf, vf[df], oacc[nf][df], 0, 0, 0);
        }
    }

    #pragma unroll
    for (int nf = 0; nf < 4; ++nf)
        #pragma unroll
        for (int j = 0; j < 4; ++j) {
            const int n = nf * 16 + l4 * 4 + j;
            if (n < 49) {
                const size_t o = ((size_t)widx * 49 + n) * 192 + (size_t)head * 32;
                out[o + l16]      = f2b(oacc[nf][0][j]);
                out[o + 16 + l16] = f2b(oacc[nf][1][j]);
            }
        }
}

// ---------- launch ----------
extern "C" void kernel_launch(void* const* d_in, const int* in_sizes, int n_in,
                              void* d_out, int out_size, void* d_ws, size_t ws_size,
                              hipStream_t stream)
{
    const float* x      = (const float*)d_in[0];
    const float* n1g    = (const float*)d_in[1];
    const float* n1b    = (const float*)d_in[2];
    const float* qkv_w  = (const float*)d_in[3];
    const float* qkv_b  = (const float*)d_in[4];
    const float* rpb    = (const float*)d_in[5];
    const float* proj_w = (const float*)d_in[6];
    const float* proj_b = (const float*)d_in[7];
    const float* n2g    = (const float*)d_in[8];
    const float* n2b    = (const float*)d_in[9];
    const float* fc1_w  = (const float*)d_in[10];
    const float* fc1_b  = (const float*)d_in[11];
    const float* fc2_w  = (const float*)d_in[12];
    const float* fc2_b  = (const float*)d_in[13];
    float* out = (float*)d_out;

    const int M = MTOK;  // 100352 = 784*128
    unsigned short* big   = (unsigned short*)d_ws;          // M*768
    unsigned short* winx  = big + (size_t)M * 768;          // M*192 (ln1-win, attn-out, ln2-out)
    unsigned short* qkvT  = winx + (size_t)M * 192;         // 576*192
    unsigned short* projT = qkvT + 576 * 192;               // 192*192
    unsigned short* fc1T  = projT + 192 * 192;              // 768*192
    unsigned short* fc2T  = fc1T + 768 * 192;               // 192*768

    // 0) weights -> bf16 transposed
    wconv_k<<<(576 * 192 + 255) / 256, 256, 0, stream>>>(qkv_w, qkvT, 192, 576);
    wconv_k<<<(192 * 192 + 255) / 256, 256, 0, stream>>>(proj_w, projT, 192, 192);
    wconv_k<<<(768 * 192 + 255) / 256, 256, 0, stream>>>(fc1_w, fc1T, 192, 768);
    wconv_k<<<(192 * 768 + 255) / 256, 256, 0, stream>>>(fc2_w, fc2T, 768, 192);

    // 1) LN1 + shift + window partition -> winx (bf16)
    ln1_window_k<<<M / 4, 256, 0, stream>>>(x, n1g, n1b, winx);
    // 2) qkv: (M,192)@(192,576) -> big
    mgemm_k<EPI_STORE_BF16><<<9 * (M / 128), 256, 0, stream>>>(
        winx, qkvT, qkv_b, big, nullptr, nullptr, 576, 192, 9);
    // 3) attention (MFMA, one wave per window×head) -> winx
    attn_mfma_k<<<2048 * 6, 64, 0, stream>>>(big, rpb, winx);
    // 4) proj + window-reverse + unshift + residual -> d_out (f32)
    mgemm_k<EPI_PROJ><<<3 * (M / 128), 256, 0, stream>>>(
        winx, projT, proj_b, nullptr, out, x, 192, 192, 3);
    // 5) LN2 -> winx (bf16)
    ln2_k<<<M / 4, 256, 0, stream>>>(out, n2g, n2b, winx);
    // 6) fc1 + GELU -> big
    mgemm_k<EPI_GELU><<<12 * (M / 128), 256, 0, stream>>>(
        winx, fc1T, fc1_b, big, nullptr, nullptr, 768, 192, 12);
    // 7) fc2 + residual -> d_out
    mgemm_k<EPI_RES><<<3 * (M / 128), 256, 0, stream>>>(
        big, fc2T, fc2_b, nullptr, out, nullptr, 192, 768, 3);
}